// Round 18
// baseline (4010.085 us; speedup 1.0000x reference)
//
#include <hip/hip_runtime.h>
#include <math.h>

// MPNN on MI355X. R18 = R17 + (1) sum-buffer memsets (4x65MB) replaced by
// straddle-row-only zeroing: only segments whose CSR runs cross a block
// boundary receive atomicAdd (<=3124/1499 rows); contained runs are plain
// stores; deg==0 rows are read with ci=0 -> fma(0,w,acc) exact, poison is
// finite. (2) edge GEMV k-loops unroll 4->8 for deeper s_load/ds_read
// prefetch. Core structure unchanged from R15/R17 (validated 3.96ms).

#define DDIM 128
#define NTOT 128000
#define HBYTES 65536000ULL   // 128000*128*4
#define EBLK 128

__device__ __forceinline__ float gelu_exact(float x) {
    return 0.5f * x * (1.0f + erff(x * 0.70710678118654752440f));
}
__device__ __forceinline__ float sigmoidf_(float x) {
    return 1.0f / (1.0f + expf(-x));
}

__global__ __launch_bounds__(256) void embed_kernel(
    const int* __restrict__ inp, const float* __restrict__ table,
    float* __restrict__ h)
{
    int gid = blockIdx.x * 256 + threadIdx.x;
    if (gid >= NTOT * 32) return;
    int row = gid >> 5;
    int q   = gid & 31;
    int b   = row / 4000;
    int n   = (row % 4000) % 1000;
    int e   = inp[b * 1000 + n];
    ((float4*)h)[gid] = ((const float4*)table)[e * 32 + q];
}

__global__ __launch_bounds__(256) void hist_kernel(
    const int* __restrict__ ni, const int* __restrict__ bi, int E,
    int* __restrict__ deg)
{
    int g = blockIdx.x * 256 + threadIdx.x;
    if (g < E)          atomicAdd(&deg[bi[g]], 1);
    else if (g < 2 * E) atomicAdd(&deg[ni[g - E]], 1);
}

__global__ __launch_bounds__(256) void blockscan_kernel(
    const int* __restrict__ deg, int* __restrict__ offp, int* __restrict__ bsum)
{
    __shared__ int s[256];
    int tid = threadIdx.x;
    int i = blockIdx.x * 256 + tid;
    int v = deg[i];
    s[tid] = v;
    __syncthreads();
    for (int off = 1; off < 256; off <<= 1) {
        int t = (tid >= off) ? s[tid - off] : 0;
        __syncthreads();
        s[tid] += t;
        __syncthreads();
    }
    offp[i] = s[tid] - v;
    if (tid == 255) bsum[blockIdx.x] = s[255];
}

__global__ __launch_bounds__(512) void bscan_kernel(
    const int* __restrict__ bsum, int* __restrict__ bexc, int nb)
{
    __shared__ int s[512];
    int t = threadIdx.x;
    int v = (t < nb) ? bsum[t] : 0;
    s[t] = v;
    __syncthreads();
    for (int off = 1; off < 512; off <<= 1) {
        int u = (t >= off) ? s[t - off] : 0;
        __syncthreads();
        s[t] += u;
        __syncthreads();
    }
    if (t < nb) bexc[t] = s[t] - v;
}

__global__ __launch_bounds__(256) void fill_kernel(
    const int* __restrict__ ni, const int* __restrict__ bi, int E,
    const int* __restrict__ offp, const int* __restrict__ bexc,
    int* __restrict__ cursor, int* __restrict__ elist, int* __restrict__ slotseg)
{
    int g = blockIdx.x * 256 + threadIdx.x;
    if (g >= 2 * E) return;
    int seg = (g < E) ? bi[g] : ni[g - E];
    int pos = atomicAdd(&cursor[seg], 1);
    int slot = offp[seg] + bexc[seg >> 8] + pos;
    elist[slot] = g;
    slotseg[slot] = seg;
}

// Find segments straddling an EBLK boundary: slotseg[b*EBLK-1]==slotseg[b*EBLK]
__global__ __launch_bounds__(256) void straddle_kernel(
    const int* __restrict__ slotseg, int nblocks,
    int* __restrict__ list, int* __restrict__ count)
{
    int b = blockIdx.x * 256 + threadIdx.x + 1;     // boundary index 1..nblocks-1
    if (b >= nblocks) return;
    int s = slotseg[b * EBLK];
    if (s >= 0 && slotseg[b * EBLK - 1] == s) {
        int pos = atomicAdd(count, 1);
        list[pos] = s;
    }
}

// Zero the DDIM floats of each straddle segment row. 2 waves/row-pair.
__global__ __launch_bounds__(64) void zero_rows_kernel(
    const int* __restrict__ list, const int* __restrict__ count,
    float* __restrict__ sbuf)
{
    int i = blockIdx.x;                 // one row per block
    if (i >= *count) return;
    int seg = list[i];
    float4* row = (float4*)(sbuf + (size_t)seg * DDIM);
    if (threadIdx.x < 32) row[threadIdx.x] = make_float4(0.f, 0.f, 0.f, 0.f);
}

// Pack Wx,Wh [128][384] into Wg[((sc*128+k)*96 + slot*16 + j)],
// sc in [0,8) = 16-col chunk; slot order wx_z, wh_z, wx_r, wh_r, wx_h, wh_h.
__global__ __launch_bounds__(256) void pack_gru_kernel(
    const float* __restrict__ Wx, const float* __restrict__ Wh,
    float* __restrict__ Wg)
{
    int idx = blockIdx.x * 256 + threadIdx.x;   // 98304 total
    if (idx >= 98304) return;
    int j    = idx & 15;
    int slot = (idx >> 4) % 6;
    int k    = (idx / 96) & 127;
    int sc   = idx / 12288;
    const float* W = (slot & 1) ? Wh : Wx;
    int gate = slot >> 1;        // 0=z,1=r,2=h
    Wg[idx] = W[k * 384 + gate * 128 + sc * 16 + j];
}

// Per-node stage-1 factorization (used ONCE for the initial p):
// p[v][0:64) = Wtop@h[v] + bin, p[v][64:128) = Wbot@h[v].
__global__ __launch_bounds__(256) void node_pre_kernel(
    const float* __restrict__ h, const float* __restrict__ Win,
    const float* __restrict__ bin, float* __restrict__ p)
{
    const int node = blockIdx.x * 256 + threadIdx.x;
    const float4* h4 = (const float4*)(h + (size_t)node * DDIM);
    float* prow = p + (size_t)node * DDIM;

    for (int c = 0; c < 4; ++c) {
        const int top   = (c < 2) ? 1 : 0;
        const int j0    = (c & 1) * 32;
        const int kbase = top ? 0 : 128;
        float acc[32];
        #pragma unroll
        for (int j = 0; j < 32; ++j) acc[j] = top ? bin[j0 + j] : 0.0f;
        for (int k4 = 0; k4 < 32; ++k4) {
            float4 hv = h4[k4];
            #pragma unroll
            for (int kk = 0; kk < 4; ++kk) {
                const float hk = (&hv.x)[kk];
                const float* wr = Win + (size_t)(kbase + k4 * 4 + kk) * 64 + j0;
                #pragma unroll
                for (int j = 0; j < 32; ++j) acc[j] = fmaf(hk, wr[j], acc[j]);
            }
        }
        float* dst = prow + (top ? 0 : 64) + j0;
        #pragma unroll
        for (int q = 0; q < 8; ++q)
            ((float4*)dst)[q] = make_float4(acc[q*4], acc[q*4+1],
                                            acc[q*4+2], acc[q*4+3]);
    }
}

// Edge MLP from precomputed p, CSR-sorted slots + fused segmented reduction.
// Activations in per-thread LDS slices (stride 65). Weights scalar-loaded.
// sbuf straddle rows MUST be pre-zeroed (atomicAdd targets).
__global__ __launch_bounds__(EBLK) void edge_mlp_kernel3(
    const int* __restrict__ ni, const int* __restrict__ bi, int E,
    const int* __restrict__ elist, const int* __restrict__ slotseg,
    const float* __restrict__ p,
    const float* __restrict__ Whid, const float* __restrict__ bhid,
    const float* __restrict__ Wout, const float* __restrict__ bout,
    float* __restrict__ sbuf)
{
    __shared__ float xs[EBLK * 65];
    __shared__ float scat[16 * 68];
    __shared__ int   segLDS[EBLK];
    __shared__ int   segedge[2];
    const int tid  = threadIdx.x;
    const int lane = tid & 63;
    const int s0   = blockIdx.x * EBLK;
    const int slot = s0 + tid;

    const int seg = slotseg[slot];
    const int g   = (seg >= 0) ? elist[slot] : 0;
    int first = 0, second = 0;
    if (seg >= 0) {
        if (g < E) { first = ni[g];     second = bi[g];     }
        else       { first = bi[g - E]; second = ni[g - E]; }
    }
    segLDS[tid] = seg;
    if (tid == 0) segedge[0] = slotseg[s0 - 1];
    if (tid == 1) segedge[1] = slotseg[s0 + EBLK];

    {
        const float4* pa = (const float4*)(p + (size_t)first  * DDIM);
        const float4* pb = (const float4*)(p + (size_t)second * DDIM + 64);
        #pragma unroll 4
        for (int q = 0; q < 16; ++q) {
            float4 a = pa[q], b = pb[q];
            xs[tid * 65 + q * 4 + 0] = gelu_exact(a.x + b.x);
            xs[tid * 65 + q * 4 + 1] = gelu_exact(a.y + b.y);
            xs[tid * 65 + q * 4 + 2] = gelu_exact(a.z + b.z);
            xs[tid * 65 + q * 4 + 3] = gelu_exact(a.w + b.w);
        }
    }

    for (int L = 0; L < 3; ++L) {
        float acc[64];
        #pragma unroll
        for (int j = 0; j < 64; ++j) acc[j] = bhid[L * 64 + j];
        #pragma unroll 8
        for (int k = 0; k < 64; ++k) {
            const float xk = xs[tid * 65 + k];
            const float* wr = Whid + (size_t)L * 4096 + (size_t)k * 64;
            #pragma unroll
            for (int j = 0; j < 64; ++j) acc[j] = fmaf(xk, wr[j], acc[j]);
        }
        #pragma unroll
        for (int j = 0; j < 64; ++j) xs[tid * 65 + j] = gelu_exact(acc[j]);
    }

    for (int half = 0; half < 2; ++half) {
        float acc[64];
        #pragma unroll
        for (int j = 0; j < 64; ++j) acc[j] = bout[half * 64 + j];
        #pragma unroll 8
        for (int k = 0; k < 64; ++k) {
            const float xk = xs[tid * 65 + k];
            const float* wr = Wout + (size_t)k * 128 + half * 64;
            #pragma unroll
            for (int j = 0; j < 64; ++j) acc[j] = fmaf(xk, wr[j], acc[j]);
        }

        int   runSeg = -2;
        float runacc = 0.0f;
        bool  leftC  = true;
        for (int b = 0; b < 8; ++b) {
            __syncthreads();
            if ((tid >> 4) == b) {
                float4* dp = (float4*)&scat[(tid & 15) * 68];
                #pragma unroll
                for (int q = 0; q < 16; ++q)
                    dp[q] = make_float4(acc[q*4], acc[q*4+1], acc[q*4+2], acc[q*4+3]);
            }
            __syncthreads();
            if (tid < 64) {
                for (int r = 0; r < 16; ++r) {
                    const int rowi = b * 16 + r;
                    const int sg = segLDS[rowi];
                    const float v = scat[r * 68 + lane];
                    if (sg != runSeg) {
                        if (runSeg >= 0) {
                            float* pp = sbuf + (size_t)runSeg * DDIM + half * 64 + lane;
                            if (leftC) *pp = runacc;
                            else       atomicAdd(pp, runacc);
                        }
                        runSeg = sg;
                        runacc = v;
                        leftC  = (rowi == 0) ? (segedge[0] != sg) : true;
                    } else {
                        runacc += v;
                    }
                }
            }
        }
        if (tid < 64 && runSeg >= 0) {
            const bool rightC = (segedge[1] != runSeg);
            float* pp = sbuf + (size_t)runSeg * DDIM + half * 64 + lane;
            if (leftC && rightC) *pp = runacc;
            else                 atomicAdd(pp, runacc);
        }
        __syncthreads();
    }
}

// Fused GRU + next-phase node_pre, register-dieted (R15, validated).
__global__ __launch_bounds__(256) void gru_fused_kernel(
    const float* __restrict__ h, float* __restrict__ msum,
    const int* __restrict__ deg,
    const float* __restrict__ Wg,
    const float* __restrict__ bi, const float* __restrict__ br,
    const float* __restrict__ Win, const float* __restrict__ binp,
    float* __restrict__ hout)
{
    __shared__ float hs[128 * 64];   // 32KB, [k][node]
    const int tid  = threadIdx.x;
    const int lane = tid & 63;
    const int part = tid >> 6;                 // 0..3
    const int nbase = blockIdx.x * 64;         // grid 2000 exact
    const int node  = nbase + lane;
    const int dg = deg[node];
    const float ci = (dg > 0) ? (1.0f / (float)dg) : 0.0f;
    const float4* mr = (const float4*)(msum + (size_t)node * DDIM);
    const float4* hr = (const float4*)(h    + (size_t)node * DDIM);

    #pragma unroll
    for (int q = 0; q < 8; ++q) {
        float4 hv = hr[part * 8 + q];
        const int k0 = part * 32 + q * 4;
        #pragma unroll
        for (int kk = 0; kk < 4; ++kk)
            hs[(k0 + kk) * 64 + lane] = (&hv.x)[kk];
    }
    __syncthreads();

    const int wch = __builtin_amdgcn_readfirstlane(part);  // wave-uniform
    float4 osc[2][4];

    #pragma unroll
    for (int s = 0; s < 2; ++s) {
        const int sc = wch * 2 + s;        // 0..7
        const int j0 = sc * 16;
        float az[16], ar[16], ax[16], ah[16];
        #pragma unroll
        for (int j = 0; j < 16; ++j) {
            az[j] = bi[j0 + j]       + br[j0 + j];
            ar[j] = bi[128 + j0 + j] + br[128 + j0 + j];
            ax[j] = bi[256 + j0 + j];
            ah[j] = br[256 + j0 + j];
        }
        for (int k4 = 0; k4 < 32; ++k4) {
            float4 mv = mr[k4];
            #pragma unroll
            for (int kk = 0; kk < 4; ++kk) {
                const int k = k4 * 4 + kk;
                const float mk = (&mv.x)[kk] * ci;
                const float hk = hs[k * 64 + lane];
                const float* wp = Wg + (size_t)(sc * 128 + k) * 96;
                #pragma unroll
                for (int j = 0; j < 16; ++j) {
                    az[j] = fmaf(mk, wp[j],      az[j]);
                    az[j] = fmaf(hk, wp[16 + j], az[j]);
                    ar[j] = fmaf(mk, wp[32 + j], ar[j]);
                    ar[j] = fmaf(hk, wp[48 + j], ar[j]);
                    ax[j] = fmaf(mk, wp[64 + j], ax[j]);
                    ah[j] = fmaf(hk, wp[80 + j], ah[j]);
                }
            }
        }
        #pragma unroll
        for (int q = 0; q < 4; ++q) {
            #pragma unroll
            for (int kk = 0; kk < 4; ++kk) {
                const int j = q * 4 + kk;
                const float z    = sigmoidf_(az[j]);
                const float r    = sigmoidf_(ar[j]);
                const float cand = tanhf(ax[j] + r * ah[j]);
                const float hv   = hs[(j0 + j) * 64 + lane];
                (&osc[s][q].x)[kk] = z * hv + (1.0f - z) * cand;
            }
        }
        float4* orow = (float4*)(hout + (size_t)node * DDIM + j0);
        #pragma unroll
        for (int q = 0; q < 4; ++q) orow[q] = osc[s][q];
    }
    __syncthreads();     // all waves done reading old hs

    #pragma unroll
    for (int s = 0; s < 2; ++s) {
        const int j0 = (wch * 2 + s) * 16;
        #pragma unroll
        for (int q = 0; q < 4; ++q)
            #pragma unroll
            for (int kk = 0; kk < 4; ++kk)
                hs[(j0 + q * 4 + kk) * 64 + lane] = (&osc[s][q].x)[kk];
    }
    __syncthreads();

    #pragma unroll
    for (int s = 0; s < 2; ++s) {
        const int sc   = wch * 2 + s;          // 0..7
        const int top  = (sc < 4) ? 1 : 0;
        const int cb   = (sc & 3) * 16;
        const int krow = top ? 0 : 128;
        float pacc[16];
        #pragma unroll
        for (int j = 0; j < 16; ++j) pacc[j] = top ? binp[cb + j] : 0.0f;
        #pragma unroll 2
        for (int k = 0; k < 128; ++k) {
            const float hk = hs[k * 64 + lane];
            const float* wr = Win + (size_t)(krow + k) * 64 + cb;
            #pragma unroll
            for (int j = 0; j < 16; ++j) pacc[j] = fmaf(hk, wr[j], pacc[j]);
        }
        float* prow = msum + (size_t)node * DDIM + (top ? 0 : 64) + cb;
        #pragma unroll
        for (int q = 0; q < 4; ++q)
            ((float4*)prow)[q] = make_float4(pacc[q*4], pacc[q*4+1],
                                             pacc[q*4+2], pacc[q*4+3]);
    }
}

// Readout: block=64, activations in LDS slice, weights direct from global.
__global__ __launch_bounds__(64) void readout_kernel(
    const float* __restrict__ h,
    const float* __restrict__ Win,  const float* __restrict__ bin,
    const float* __restrict__ Whid, const float* __restrict__ bhid,
    const float* __restrict__ Wout, const float* __restrict__ bout,
    float* __restrict__ out)
{
    __shared__ float xs[64 * 65];
    const int tid = threadIdx.x;
    const int row = blockIdx.x * 64 + tid;
    const int b = row / 1000, n = row % 1000;
    const float4* xrow = (const float4*)(h + ((size_t)b * 4000 + n) * DDIM);

    {
        float acc[64];
        #pragma unroll
        for (int j = 0; j < 64; ++j) acc[j] = bin[j];
        #pragma unroll 2
        for (int k4 = 0; k4 < 32; ++k4) {
            float4 xv = xrow[k4];
            #pragma unroll
            for (int kk = 0; kk < 4; ++kk) {
                const float xk = (&xv.x)[kk];
                const float* wr = Win + (size_t)(k4 * 4 + kk) * 64;
                #pragma unroll
                for (int j = 0; j < 64; ++j) acc[j] = fmaf(xk, wr[j], acc[j]);
            }
        }
        #pragma unroll
        for (int j = 0; j < 64; ++j) xs[tid * 65 + j] = gelu_exact(acc[j]);
    }

    for (int L = 0; L < 3; ++L) {
        float acc[64];
        #pragma unroll
        for (int j = 0; j < 64; ++j) acc[j] = bhid[L * 64 + j];
        #pragma unroll 4
        for (int k = 0; k < 64; ++k) {
            const float xk = xs[tid * 65 + k];
            const float* wr = Whid + (size_t)L * 4096 + (size_t)k * 64;
            #pragma unroll
            for (int j = 0; j < 64; ++j) acc[j] = fmaf(xk, wr[j], acc[j]);
        }
        #pragma unroll
        for (int j = 0; j < 64; ++j) xs[tid * 65 + j] = gelu_exact(acc[j]);
    }

    float acc[10];
    #pragma unroll
    for (int pj = 0; pj < 10; ++pj) acc[pj] = bout[pj];
    #pragma unroll 4
    for (int k = 0; k < 64; ++k) {
        const float xk = xs[tid * 65 + k];
        const float* wr = Wout + k * 10;
        #pragma unroll
        for (int pj = 0; pj < 10; ++pj) acc[pj] = fmaf(xk, wr[pj], acc[pj]);
    }
    #pragma unroll
    for (int pj = 0; pj < 10; ++pj) out[(size_t)row * 10 + pj] = acc[pj];
}

extern "C" void kernel_launch(void* const* d_in, const int* in_sizes, int n_in,
                              void* d_out, int out_size, void* d_ws, size_t ws_size,
                              hipStream_t stream) {
    const int*   node_inputs = (const int*)d_in[0];
    const int*   ni_int = (const int*)d_in[1];
    const int*   bi_int = (const int*)d_in[2];
    const int*   ni_tmp = (const int*)d_in[3];
    const int*   bi_tmp = (const int*)d_in[4];
    const float* embed  = (const float*)d_in[5];
    const float* mWin   = (const float*)d_in[6];
    const float* mbin   = (const float*)d_in[7];
    const float* mWhid  = (const float*)d_in[8];
    const float* mbhid  = (const float*)d_in[9];
    const float* mWout  = (const float*)d_in[10];
    const float* mbout  = (const float*)d_in[11];
    const float* roWin  = (const float*)d_in[12];
    const float* robin  = (const float*)d_in[13];
    const float* roWhid = (const float*)d_in[14];
    const float* robhid = (const float*)d_in[15];
    const float* roWout = (const float*)d_in[16];
    const float* robout = (const float*)d_in[17];
    const float* giWx = (const float*)d_in[18];
    const float* giWh = (const float*)d_in[19];
    const float* gibi = (const float*)d_in[20];
    const float* gibr = (const float*)d_in[21];
    const float* gtWx = (const float*)d_in[22];
    const float* gtWh = (const float*)d_in[23];
    const float* gtbi = (const float*)d_in[24];
    const float* gtbr = (const float*)d_in[25];
    float* out = (float*)d_out;

    const int E_INT = 200000, E_TMP = 96000;
    const int NSLOT_I = 400000;   // 3125*128 exact
    const int NSLOT_T = 192000;   // 1500*128 exact
    const int NBLK_I = NSLOT_I / EBLK;   // 3125
    const int NBLK_T = NSLOT_T / EBLK;   // 1500

    char* ws = (char*)d_ws;
    float* B0 = (float*)(ws);
    float* B1 = (float*)(ws + HBYTES);
    float* B2 = (float*)(ws + 2 * HBYTES);
    char*  ib = ws + 3 * HBYTES;

    int* deg_i   = (int*)(ib);
    int* deg_t   = (int*)(ib + 512000);
    int* offp_i  = (int*)(ib + 1024000);
    int* offp_t  = (int*)(ib + 1536000);
    int* bexc_i  = (int*)(ib + 2048000);
    int* bexc_t  = (int*)(ib + 2052096);
    int* bsum    = (int*)(ib + 2056192);
    int* cursor  = (int*)(ib + 2060288);
    int* el_i    = (int*)(ib + 2572288);
    int* el_t    = (int*)(ib + 4172288);
    int* ssi_raw = (int*)(ib + 4940288);
    int* sst_raw = (int*)(ib + 6540296);
    float* wg_i  = (float*)(ib + 7308352);   // 98304 floats = 384KB
    float* wg_t  = (float*)(ib + 7701568);   // 98304 floats
    int* str_i   = (int*)(ib + 8094784);     // straddle list int (3125 ints)
    int* str_t   = (int*)(ib + 8107384);     // straddle list tmp (1500 ints)
    int* strc_i  = (int*)(ib + 8113484);     // counts
    int* strc_t  = (int*)(ib + 8113488);
    int* ssi = ssi_raw + 1;
    int* sst = sst_raw + 1;

    embed_kernel<<<16000, 256, 0, stream>>>(node_inputs, embed, B0);

    hipMemsetAsync(deg_i, 0, NTOT * sizeof(int), stream);
    hipMemsetAsync(deg_t, 0, NTOT * sizeof(int), stream);
    hist_kernel<<<(2 * E_INT + 255) / 256, 256, 0, stream>>>(ni_int, bi_int, E_INT, deg_i);
    hist_kernel<<<(2 * E_TMP + 255) / 256, 256, 0, stream>>>(ni_tmp, bi_tmp, E_TMP, deg_t);

    hipMemsetAsync(ssi_raw, 0xFF, (size_t)(NSLOT_I + 2) * sizeof(int), stream);
    hipMemsetAsync(sst_raw, 0xFF, (size_t)(NSLOT_T + 2) * sizeof(int), stream);

    blockscan_kernel<<<500, 256, 0, stream>>>(deg_i, offp_i, bsum);
    bscan_kernel<<<1, 512, 0, stream>>>(bsum, bexc_i, 500);
    hipMemsetAsync(cursor, 0, NTOT * sizeof(int), stream);
    fill_kernel<<<(2 * E_INT + 255) / 256, 256, 0, stream>>>(
        ni_int, bi_int, E_INT, offp_i, bexc_i, cursor, el_i, ssi);

    blockscan_kernel<<<500, 256, 0, stream>>>(deg_t, offp_t, bsum);
    bscan_kernel<<<1, 512, 0, stream>>>(bsum, bexc_t, 500);
    hipMemsetAsync(cursor, 0, NTOT * sizeof(int), stream);
    fill_kernel<<<(2 * E_TMP + 255) / 256, 256, 0, stream>>>(
        ni_tmp, bi_tmp, E_TMP, offp_t, bexc_t, cursor, el_t, sst);

    // straddle segment lists (segments that receive atomicAdd)
    hipMemsetAsync(strc_i, 0, sizeof(int), stream);
    hipMemsetAsync(strc_t, 0, sizeof(int), stream);
    straddle_kernel<<<(NBLK_I + 255) / 256, 256, 0, stream>>>(ssi, NBLK_I, str_i, strc_i);
    straddle_kernel<<<(NBLK_T + 255) / 256, 256, 0, stream>>>(sst, NBLK_T, str_t, strc_t);

    pack_gru_kernel<<<384, 256, 0, stream>>>(giWx, giWh, wg_i);
    pack_gru_kernel<<<384, 256, 0, stream>>>(gtWx, gtWh, wg_t);

    // initial p
    node_pre_kernel<<<NTOT / 256, 256, 0, stream>>>(B0, mWin, mbin, B1);

    // rotation: X=h, Y=p, Z=free
    float* X = B0; float* Y = B1; float* Z = B2;
    for (int ph = 0; ph < 4; ++ph) {
        const bool isInt = (ph % 2 == 0);
        if (isInt) {
            zero_rows_kernel<<<NBLK_I, 64, 0, stream>>>(str_i, strc_i, Z);
            edge_mlp_kernel3<<<NBLK_I, EBLK, 0, stream>>>(
                ni_int, bi_int, E_INT, el_i, ssi, Y,
                mWhid, mbhid, mWout, mbout, Z);
            gru_fused_kernel<<<NTOT / 64, 256, 0, stream>>>(
                X, Z, deg_i, wg_i, gibi, gibr, mWin, mbin, Y);
        } else {
            zero_rows_kernel<<<NBLK_T, 64, 0, stream>>>(str_t, strc_t, Z);
            edge_mlp_kernel3<<<NBLK_T, EBLK, 0, stream>>>(
                ni_tmp, bi_tmp, E_TMP, el_t, sst, Y,
                mWhid, mbhid, mWout, mbout, Z);
            gru_fused_kernel<<<NTOT / 64, 256, 0, stream>>>(
                X, Z, deg_t, wg_t, gtbi, gtbr, mWin, mbin, Y);
        }
        // h' is in Y, p' is in Z, old X becomes free
        float* oldX = X;  X = Y;  Y = Z;  Z = oldX;
    }

    readout_kernel<<<500, 64, 0, stream>>>(
        X, roWin, robin, roWhid, robhid, roWout, robout, out);
}

// Round 19
// 3949.531 us; speedup vs baseline: 1.0153x; 1.0153x over previous
//
#include <hip/hip_runtime.h>
#include <math.h>

// MPNN on MI355X. R19 = best-of: R17 edge (unroll 4, measured 561-573us)
// + R18 straddle-row zeroing (replaces 4x65MB memsets; only atomicAdd-
// target rows need pre-zeroing). Core structure validated over R15/R17/R18:
// CSR-sorted edge MLP (per-thread LDS activation slices, scalar weights,
// fused block segmented reduction) + register-dieted fused GRU/node_pre
// (16-col sub-chunks, h-only LDS, packed weights) + 3-buffer rotation.
// Known constraints (measured): >=128 fp32 accs/thread -> occupancy cliff;
// reg-resident arrays across GEMV stages -> AGPR shuttle blowup (R16);
// nontemporal stores break XCD coherence (R12); fp32 atomics are per-lane
// line-granularity memory ops (R2/R3); bf16 excluded by 6.35e-4 threshold.

#define DDIM 128
#define NTOT 128000
#define HBYTES 65536000ULL   // 128000*128*4
#define EBLK 128

__device__ __forceinline__ float gelu_exact(float x) {
    return 0.5f * x * (1.0f + erff(x * 0.70710678118654752440f));
}
__device__ __forceinline__ float sigmoidf_(float x) {
    return 1.0f / (1.0f + expf(-x));
}

__global__ __launch_bounds__(256) void embed_kernel(
    const int* __restrict__ inp, const float* __restrict__ table,
    float* __restrict__ h)
{
    int gid = blockIdx.x * 256 + threadIdx.x;
    if (gid >= NTOT * 32) return;
    int row = gid >> 5;
    int q   = gid & 31;
    int b   = row / 4000;
    int n   = (row % 4000) % 1000;
    int e   = inp[b * 1000 + n];
    ((float4*)h)[gid] = ((const float4*)table)[e * 32 + q];
}

__global__ __launch_bounds__(256) void hist_kernel(
    const int* __restrict__ ni, const int* __restrict__ bi, int E,
    int* __restrict__ deg)
{
    int g = blockIdx.x * 256 + threadIdx.x;
    if (g < E)          atomicAdd(&deg[bi[g]], 1);
    else if (g < 2 * E) atomicAdd(&deg[ni[g - E]], 1);
}

__global__ __launch_bounds__(256) void blockscan_kernel(
    const int* __restrict__ deg, int* __restrict__ offp, int* __restrict__ bsum)
{
    __shared__ int s[256];
    int tid = threadIdx.x;
    int i = blockIdx.x * 256 + tid;
    int v = deg[i];
    s[tid] = v;
    __syncthreads();
    for (int off = 1; off < 256; off <<= 1) {
        int t = (tid >= off) ? s[tid - off] : 0;
        __syncthreads();
        s[tid] += t;
        __syncthreads();
    }
    offp[i] = s[tid] - v;
    if (tid == 255) bsum[blockIdx.x] = s[255];
}

__global__ __launch_bounds__(512) void bscan_kernel(
    const int* __restrict__ bsum, int* __restrict__ bexc, int nb)
{
    __shared__ int s[512];
    int t = threadIdx.x;
    int v = (t < nb) ? bsum[t] : 0;
    s[t] = v;
    __syncthreads();
    for (int off = 1; off < 512; off <<= 1) {
        int u = (t >= off) ? s[t - off] : 0;
        __syncthreads();
        s[t] += u;
        __syncthreads();
    }
    if (t < nb) bexc[t] = s[t] - v;
}

__global__ __launch_bounds__(256) void fill_kernel(
    const int* __restrict__ ni, const int* __restrict__ bi, int E,
    const int* __restrict__ offp, const int* __restrict__ bexc,
    int* __restrict__ cursor, int* __restrict__ elist, int* __restrict__ slotseg)
{
    int g = blockIdx.x * 256 + threadIdx.x;
    if (g >= 2 * E) return;
    int seg = (g < E) ? bi[g] : ni[g - E];
    int pos = atomicAdd(&cursor[seg], 1);
    int slot = offp[seg] + bexc[seg >> 8] + pos;
    elist[slot] = g;
    slotseg[slot] = seg;
}

// Segments straddling an EBLK boundary (the only atomicAdd targets).
__global__ __launch_bounds__(256) void straddle_kernel(
    const int* __restrict__ slotseg, int nblocks,
    int* __restrict__ list, int* __restrict__ count)
{
    int b = blockIdx.x * 256 + threadIdx.x + 1;
    if (b >= nblocks) return;
    int s = slotseg[b * EBLK];
    if (s >= 0 && slotseg[b * EBLK - 1] == s) {
        int pos = atomicAdd(count, 1);
        list[pos] = s;
    }
}

__global__ __launch_bounds__(64) void zero_rows_kernel(
    const int* __restrict__ list, const int* __restrict__ count,
    float* __restrict__ sbuf)
{
    int i = blockIdx.x;
    if (i >= *count) return;
    int seg = list[i];
    float4* row = (float4*)(sbuf + (size_t)seg * DDIM);
    if (threadIdx.x < 32) row[threadIdx.x] = make_float4(0.f, 0.f, 0.f, 0.f);
}

// Pack Wx,Wh [128][384] into Wg[((sc*128+k)*96 + slot*16 + j)].
__global__ __launch_bounds__(256) void pack_gru_kernel(
    const float* __restrict__ Wx, const float* __restrict__ Wh,
    float* __restrict__ Wg)
{
    int idx = blockIdx.x * 256 + threadIdx.x;   // 98304 total
    if (idx >= 98304) return;
    int j    = idx & 15;
    int slot = (idx >> 4) % 6;
    int k    = (idx / 96) & 127;
    int sc   = idx / 12288;
    const float* W = (slot & 1) ? Wh : Wx;
    int gate = slot >> 1;
    Wg[idx] = W[k * 384 + gate * 128 + sc * 16 + j];
}

// Initial p only: p[v][0:64)=Wtop@h[v]+bin, p[v][64:128)=Wbot@h[v].
__global__ __launch_bounds__(256) void node_pre_kernel(
    const float* __restrict__ h, const float* __restrict__ Win,
    const float* __restrict__ bin, float* __restrict__ p)
{
    const int node = blockIdx.x * 256 + threadIdx.x;
    const float4* h4 = (const float4*)(h + (size_t)node * DDIM);
    float* prow = p + (size_t)node * DDIM;

    for (int c = 0; c < 4; ++c) {
        const int top   = (c < 2) ? 1 : 0;
        const int j0    = (c & 1) * 32;
        const int kbase = top ? 0 : 128;
        float acc[32];
        #pragma unroll
        for (int j = 0; j < 32; ++j) acc[j] = top ? bin[j0 + j] : 0.0f;
        for (int k4 = 0; k4 < 32; ++k4) {
            float4 hv = h4[k4];
            #pragma unroll
            for (int kk = 0; kk < 4; ++kk) {
                const float hk = (&hv.x)[kk];
                const float* wr = Win + (size_t)(kbase + k4 * 4 + kk) * 64 + j0;
                #pragma unroll
                for (int j = 0; j < 32; ++j) acc[j] = fmaf(hk, wr[j], acc[j]);
            }
        }
        float* dst = prow + (top ? 0 : 64) + j0;
        #pragma unroll
        for (int q = 0; q < 8; ++q)
            ((float4*)dst)[q] = make_float4(acc[q*4], acc[q*4+1],
                                            acc[q*4+2], acc[q*4+3]);
    }
}

// Edge MLP: per-thread LDS activation slices, scalar weights, fused
// segmented reduction. Straddle rows of sbuf must be pre-zeroed.
__global__ __launch_bounds__(EBLK) void edge_mlp_kernel3(
    const int* __restrict__ ni, const int* __restrict__ bi, int E,
    const int* __restrict__ elist, const int* __restrict__ slotseg,
    const float* __restrict__ p,
    const float* __restrict__ Whid, const float* __restrict__ bhid,
    const float* __restrict__ Wout, const float* __restrict__ bout,
    float* __restrict__ sbuf)
{
    __shared__ float xs[EBLK * 65];
    __shared__ float scat[16 * 68];
    __shared__ int   segLDS[EBLK];
    __shared__ int   segedge[2];
    const int tid  = threadIdx.x;
    const int lane = tid & 63;
    const int s0   = blockIdx.x * EBLK;
    const int slot = s0 + tid;

    const int seg = slotseg[slot];
    const int g   = (seg >= 0) ? elist[slot] : 0;
    int first = 0, second = 0;
    if (seg >= 0) {
        if (g < E) { first = ni[g];     second = bi[g];     }
        else       { first = bi[g - E]; second = ni[g - E]; }
    }
    segLDS[tid] = seg;
    if (tid == 0) segedge[0] = slotseg[s0 - 1];
    if (tid == 1) segedge[1] = slotseg[s0 + EBLK];

    {
        const float4* pa = (const float4*)(p + (size_t)first  * DDIM);
        const float4* pb = (const float4*)(p + (size_t)second * DDIM + 64);
        #pragma unroll 4
        for (int q = 0; q < 16; ++q) {
            float4 a = pa[q], b = pb[q];
            xs[tid * 65 + q * 4 + 0] = gelu_exact(a.x + b.x);
            xs[tid * 65 + q * 4 + 1] = gelu_exact(a.y + b.y);
            xs[tid * 65 + q * 4 + 2] = gelu_exact(a.z + b.z);
            xs[tid * 65 + q * 4 + 3] = gelu_exact(a.w + b.w);
        }
    }

    for (int L = 0; L < 3; ++L) {
        float acc[64];
        #pragma unroll
        for (int j = 0; j < 64; ++j) acc[j] = bhid[L * 64 + j];
        #pragma unroll 4
        for (int k = 0; k < 64; ++k) {
            const float xk = xs[tid * 65 + k];
            const float* wr = Whid + (size_t)L * 4096 + (size_t)k * 64;
            #pragma unroll
            for (int j = 0; j < 64; ++j) acc[j] = fmaf(xk, wr[j], acc[j]);
        }
        #pragma unroll
        for (int j = 0; j < 64; ++j) xs[tid * 65 + j] = gelu_exact(acc[j]);
    }

    for (int half = 0; half < 2; ++half) {
        float acc[64];
        #pragma unroll
        for (int j = 0; j < 64; ++j) acc[j] = bout[half * 64 + j];
        #pragma unroll 4
        for (int k = 0; k < 64; ++k) {
            const float xk = xs[tid * 65 + k];
            const float* wr = Wout + (size_t)k * 128 + half * 64;
            #pragma unroll
            for (int j = 0; j < 64; ++j) acc[j] = fmaf(xk, wr[j], acc[j]);
        }

        int   runSeg = -2;
        float runacc = 0.0f;
        bool  leftC  = true;
        for (int b = 0; b < 8; ++b) {
            __syncthreads();
            if ((tid >> 4) == b) {
                float4* dp = (float4*)&scat[(tid & 15) * 68];
                #pragma unroll
                for (int q = 0; q < 16; ++q)
                    dp[q] = make_float4(acc[q*4], acc[q*4+1], acc[q*4+2], acc[q*4+3]);
            }
            __syncthreads();
            if (tid < 64) {
                for (int r = 0; r < 16; ++r) {
                    const int rowi = b * 16 + r;
                    const int sg = segLDS[rowi];
                    const float v = scat[r * 68 + lane];
                    if (sg != runSeg) {
                        if (runSeg >= 0) {
                            float* pp = sbuf + (size_t)runSeg * DDIM + half * 64 + lane;
                            if (leftC) *pp = runacc;
                            else       atomicAdd(pp, runacc);
                        }
                        runSeg = sg;
                        runacc = v;
                        leftC  = (rowi == 0) ? (segedge[0] != sg) : true;
                    } else {
                        runacc += v;
                    }
                }
            }
        }
        if (tid < 64 && runSeg >= 0) {
            const bool rightC = (segedge[1] != runSeg);
            float* pp = sbuf + (size_t)runSeg * DDIM + half * 64 + lane;
            if (leftC && rightC) *pp = runacc;
            else                 atomicAdd(pp, runacc);
        }
        __syncthreads();
    }
}

// Fused GRU + next-phase node_pre, register-dieted (R15, validated).
__global__ __launch_bounds__(256) void gru_fused_kernel(
    const float* __restrict__ h, float* __restrict__ msum,
    const int* __restrict__ deg,
    const float* __restrict__ Wg,
    const float* __restrict__ bi, const float* __restrict__ br,
    const float* __restrict__ Win, const float* __restrict__ binp,
    float* __restrict__ hout)
{
    __shared__ float hs[128 * 64];   // 32KB, [k][node]
    const int tid  = threadIdx.x;
    const int lane = tid & 63;
    const int part = tid >> 6;
    const int nbase = blockIdx.x * 64;         // grid 2000 exact
    const int node  = nbase + lane;
    const int dg = deg[node];
    const float ci = (dg > 0) ? (1.0f / (float)dg) : 0.0f;
    const float4* mr = (const float4*)(msum + (size_t)node * DDIM);
    const float4* hr = (const float4*)(h    + (size_t)node * DDIM);

    #pragma unroll
    for (int q = 0; q < 8; ++q) {
        float4 hv = hr[part * 8 + q];
        const int k0 = part * 32 + q * 4;
        #pragma unroll
        for (int kk = 0; kk < 4; ++kk)
            hs[(k0 + kk) * 64 + lane] = (&hv.x)[kk];
    }
    __syncthreads();

    const int wch = __builtin_amdgcn_readfirstlane(part);
    float4 osc[2][4];

    #pragma unroll
    for (int s = 0; s < 2; ++s) {
        const int sc = wch * 2 + s;
        const int j0 = sc * 16;
        float az[16], ar[16], ax[16], ah[16];
        #pragma unroll
        for (int j = 0; j < 16; ++j) {
            az[j] = bi[j0 + j]       + br[j0 + j];
            ar[j] = bi[128 + j0 + j] + br[128 + j0 + j];
            ax[j] = bi[256 + j0 + j];
            ah[j] = br[256 + j0 + j];
        }
        for (int k4 = 0; k4 < 32; ++k4) {
            float4 mv = mr[k4];
            #pragma unroll
            for (int kk = 0; kk < 4; ++kk) {
                const int k = k4 * 4 + kk;
                const float mk = (&mv.x)[kk] * ci;
                const float hk = hs[k * 64 + lane];
                const float* wp = Wg + (size_t)(sc * 128 + k) * 96;
                #pragma unroll
                for (int j = 0; j < 16; ++j) {
                    az[j] = fmaf(mk, wp[j],      az[j]);
                    az[j] = fmaf(hk, wp[16 + j], az[j]);
                    ar[j] = fmaf(mk, wp[32 + j], ar[j]);
                    ar[j] = fmaf(hk, wp[48 + j], ar[j]);
                    ax[j] = fmaf(mk, wp[64 + j], ax[j]);
                    ah[j] = fmaf(hk, wp[80 + j], ah[j]);
                }
            }
        }
        #pragma unroll
        for (int q = 0; q < 4; ++q) {
            #pragma unroll
            for (int kk = 0; kk < 4; ++kk) {
                const int j = q * 4 + kk;
                const float z    = sigmoidf_(az[j]);
                const float r    = sigmoidf_(ar[j]);
                const float cand = tanhf(ax[j] + r * ah[j]);
                const float hv   = hs[(j0 + j) * 64 + lane];
                (&osc[s][q].x)[kk] = z * hv + (1.0f - z) * cand;
            }
        }
        float4* orow = (float4*)(hout + (size_t)node * DDIM + j0);
        #pragma unroll
        for (int q = 0; q < 4; ++q) orow[q] = osc[s][q];
    }
    __syncthreads();

    #pragma unroll
    for (int s = 0; s < 2; ++s) {
        const int j0 = (wch * 2 + s) * 16;
        #pragma unroll
        for (int q = 0; q < 4; ++q)
            #pragma unroll
            for (int kk = 0; kk < 4; ++kk)
                hs[(j0 + q * 4 + kk) * 64 + lane] = (&osc[s][q].x)[kk];
    }
    __syncthreads();

    #pragma unroll
    for (int s = 0; s < 2; ++s) {
        const int sc   = wch * 2 + s;
        const int top  = (sc < 4) ? 1 : 0;
        const int cb   = (sc & 3) * 16;
        const int krow = top ? 0 : 128;
        float pacc[16];
        #pragma unroll
        for (int j = 0; j < 16; ++j) pacc[j] = top ? binp[cb + j] : 0.0f;
        #pragma unroll 2
        for (int k = 0; k < 128; ++k) {
            const float hk = hs[k * 64 + lane];
            const float* wr = Win + (size_t)(krow + k) * 64 + cb;
            #pragma unroll
            for (int j = 0; j < 16; ++j) pacc[j] = fmaf(hk, wr[j], pacc[j]);
        }
        float* prow = msum + (size_t)node * DDIM + (top ? 0 : 64) + cb;
        #pragma unroll
        for (int q = 0; q < 4; ++q)
            ((float4*)prow)[q] = make_float4(pacc[q*4], pacc[q*4+1],
                                             pacc[q*4+2], pacc[q*4+3]);
    }
}

// Readout: block=64, LDS activation slices, scalar weights.
__global__ __launch_bounds__(64) void readout_kernel(
    const float* __restrict__ h,
    const float* __restrict__ Win,  const float* __restrict__ bin,
    const float* __restrict__ Whid, const float* __restrict__ bhid,
    const float* __restrict__ Wout, const float* __restrict__ bout,
    float* __restrict__ out)
{
    __shared__ float xs[64 * 65];
    const int tid = threadIdx.x;
    const int row = blockIdx.x * 64 + tid;
    const int b = row / 1000, n = row % 1000;
    const float4* xrow = (const float4*)(h + ((size_t)b * 4000 + n) * DDIM);

    {
        float acc[64];
        #pragma unroll
        for (int j = 0; j < 64; ++j) acc[j] = bin[j];
        #pragma unroll 2
        for (int k4 = 0; k4 < 32; ++k4) {
            float4 xv = xrow[k4];
            #pragma unroll
            for (int kk = 0; kk < 4; ++kk) {
                const float xk = (&xv.x)[kk];
                const float* wr = Win + (size_t)(k4 * 4 + kk) * 64;
                #pragma unroll
                for (int j = 0; j < 64; ++j) acc[j] = fmaf(xk, wr[j], acc[j]);
            }
        }
        #pragma unroll
        for (int j = 0; j < 64; ++j) xs[tid * 65 + j] = gelu_exact(acc[j]);
    }

    for (int L = 0; L < 3; ++L) {
        float acc[64];
        #pragma unroll
        for (int j = 0; j < 64; ++j) acc[j] = bhid[L * 64 + j];
        #pragma unroll 4
        for (int k = 0; k < 64; ++k) {
            const float xk = xs[tid * 65 + k];
            const float* wr = Whid + (size_t)L * 4096 + (size_t)k * 64;
            #pragma unroll
            for (int j = 0; j < 64; ++j) acc[j] = fmaf(xk, wr[j], acc[j]);
        }
        #pragma unroll
        for (int j = 0; j < 64; ++j) xs[tid * 65 + j] = gelu_exact(acc[j]);
    }

    float acc[10];
    #pragma unroll
    for (int pj = 0; pj < 10; ++pj) acc[pj] = bout[pj];
    #pragma unroll 4
    for (int k = 0; k < 64; ++k) {
        const float xk = xs[tid * 65 + k];
        const float* wr = Wout + k * 10;
        #pragma unroll
        for (int pj = 0; pj < 10; ++pj) acc[pj] = fmaf(xk, wr[pj], acc[pj]);
    }
    #pragma unroll
    for (int pj = 0; pj < 10; ++pj) out[(size_t)row * 10 + pj] = acc[pj];
}

extern "C" void kernel_launch(void* const* d_in, const int* in_sizes, int n_in,
                              void* d_out, int out_size, void* d_ws, size_t ws_size,
                              hipStream_t stream) {
    const int*   node_inputs = (const int*)d_in[0];
    const int*   ni_int = (const int*)d_in[1];
    const int*   bi_int = (const int*)d_in[2];
    const int*   ni_tmp = (const int*)d_in[3];
    const int*   bi_tmp = (const int*)d_in[4];
    const float* embed  = (const float*)d_in[5];
    const float* mWin   = (const float*)d_in[6];
    const float* mbin   = (const float*)d_in[7];
    const float* mWhid  = (const float*)d_in[8];
    const float* mbhid  = (const float*)d_in[9];
    const float* mWout  = (const float*)d_in[10];
    const float* mbout  = (const float*)d_in[11];
    const float* roWin  = (const float*)d_in[12];
    const float* robin  = (const float*)d_in[13];
    const float* roWhid = (const float*)d_in[14];
    const float* robhid = (const float*)d_in[15];
    const float* roWout = (const float*)d_in[16];
    const float* robout = (const float*)d_in[17];
    const float* giWx = (const float*)d_in[18];
    const float* giWh = (const float*)d_in[19];
    const float* gibi = (const float*)d_in[20];
    const float* gibr = (const float*)d_in[21];
    const float* gtWx = (const float*)d_in[22];
    const float* gtWh = (const float*)d_in[23];
    const float* gtbi = (const float*)d_in[24];
    const float* gtbr = (const float*)d_in[25];
    float* out = (float*)d_out;

    const int E_INT = 200000, E_TMP = 96000;
    const int NSLOT_I = 400000;   // 3125*128 exact
    const int NSLOT_T = 192000;   // 1500*128 exact
    const int NBLK_I = NSLOT_I / EBLK;
    const int NBLK_T = NSLOT_T / EBLK;

    char* ws = (char*)d_ws;
    float* B0 = (float*)(ws);
    float* B1 = (float*)(ws + HBYTES);
    float* B2 = (float*)(ws + 2 * HBYTES);
    char*  ib = ws + 3 * HBYTES;

    int* deg_i   = (int*)(ib);
    int* deg_t   = (int*)(ib + 512000);
    int* offp_i  = (int*)(ib + 1024000);
    int* offp_t  = (int*)(ib + 1536000);
    int* bexc_i  = (int*)(ib + 2048000);
    int* bexc_t  = (int*)(ib + 2052096);
    int* bsum    = (int*)(ib + 2056192);
    int* cursor  = (int*)(ib + 2060288);
    int* el_i    = (int*)(ib + 2572288);
    int* el_t    = (int*)(ib + 4172288);
    int* ssi_raw = (int*)(ib + 4940288);
    int* sst_raw = (int*)(ib + 6540296);
    float* wg_i  = (float*)(ib + 7308352);
    float* wg_t  = (float*)(ib + 7701568);
    int* str_i   = (int*)(ib + 8094784);
    int* str_t   = (int*)(ib + 8107384);
    int* strc_i  = (int*)(ib + 8113484);
    int* strc_t  = (int*)(ib + 8113488);
    int* ssi = ssi_raw + 1;
    int* sst = sst_raw + 1;

    embed_kernel<<<16000, 256, 0, stream>>>(node_inputs, embed, B0);

    hipMemsetAsync(deg_i, 0, NTOT * sizeof(int), stream);
    hipMemsetAsync(deg_t, 0, NTOT * sizeof(int), stream);
    hist_kernel<<<(2 * E_INT + 255) / 256, 256, 0, stream>>>(ni_int, bi_int, E_INT, deg_i);
    hist_kernel<<<(2 * E_TMP + 255) / 256, 256, 0, stream>>>(ni_tmp, bi_tmp, E_TMP, deg_t);

    hipMemsetAsync(ssi_raw, 0xFF, (size_t)(NSLOT_I + 2) * sizeof(int), stream);
    hipMemsetAsync(sst_raw, 0xFF, (size_t)(NSLOT_T + 2) * sizeof(int), stream);

    blockscan_kernel<<<500, 256, 0, stream>>>(deg_i, offp_i, bsum);
    bscan_kernel<<<1, 512, 0, stream>>>(bsum, bexc_i, 500);
    hipMemsetAsync(cursor, 0, NTOT * sizeof(int), stream);
    fill_kernel<<<(2 * E_INT + 255) / 256, 256, 0, stream>>>(
        ni_int, bi_int, E_INT, offp_i, bexc_i, cursor, el_i, ssi);

    blockscan_kernel<<<500, 256, 0, stream>>>(deg_t, offp_t, bsum);
    bscan_kernel<<<1, 512, 0, stream>>>(bsum, bexc_t, 500);
    hipMemsetAsync(cursor, 0, NTOT * sizeof(int), stream);
    fill_kernel<<<(2 * E_TMP + 255) / 256, 256, 0, stream>>>(
        ni_tmp, bi_tmp, E_TMP, offp_t, bexc_t, cursor, el_t, sst);

    hipMemsetAsync(strc_i, 0, sizeof(int), stream);
    hipMemsetAsync(strc_t, 0, sizeof(int), stream);
    straddle_kernel<<<(NBLK_I + 255) / 256, 256, 0, stream>>>(ssi, NBLK_I, str_i, strc_i);
    straddle_kernel<<<(NBLK_T + 255) / 256, 256, 0, stream>>>(sst, NBLK_T, str_t, strc_t);

    pack_gru_kernel<<<384, 256, 0, stream>>>(giWx, giWh, wg_i);
    pack_gru_kernel<<<384, 256, 0, stream>>>(gtWx, gtWh, wg_t);

    node_pre_kernel<<<NTOT / 256, 256, 0, stream>>>(B0, mWin, mbin, B1);

    // rotation: X=h, Y=p, Z=free
    float* X = B0; float* Y = B1; float* Z = B2;
    for (int ph = 0; ph < 4; ++ph) {
        const bool isInt = (ph % 2 == 0);
        if (isInt) {
            zero_rows_kernel<<<NBLK_I, 64, 0, stream>>>(str_i, strc_i, Z);
            edge_mlp_kernel3<<<NBLK_I, EBLK, 0, stream>>>(
                ni_int, bi_int, E_INT, el_i, ssi, Y,
                mWhid, mbhid, mWout, mbout, Z);
            gru_fused_kernel<<<NTOT / 64, 256, 0, stream>>>(
                X, Z, deg_i, wg_i, gibi, gibr, mWin, mbin, Y);
        } else {
            zero_rows_kernel<<<NBLK_T, 64, 0, stream>>>(str_t, strc_t, Z);
            edge_mlp_kernel3<<<NBLK_T, EBLK, 0, stream>>>(
                ni_tmp, bi_tmp, E_TMP, el_t, sst, Y,
                mWhid, mbhid, mWout, mbout, Z);
            gru_fused_kernel<<<NTOT / 64, 256, 0, stream>>>(
                X, Z, deg_t, wg_t, gtbi, gtbr, mWin, mbin, Y);
        }
        float* oldX = X;  X = Y;  Y = Z;  Z = oldX;
    }

    readout_kernel<<<500, 64, 0, stream>>>(
        X, roWin, robin, roWhid, robhid, roWout, robout, out);
}